// Round 1
// baseline (795.087 us; speedup 1.0000x reference)
//
#include <hip/hip_runtime.h>

#define B_ 8
#define T_ 1024
#define C_ 1024
#define E_ 8
#define H_ 4096

typedef float v4f __attribute__((ext_vector_type(4)));
typedef short v8s __attribute__((ext_vector_type(8)));

__device__ __forceinline__ unsigned short f2bf(float f) {
  union { float f; unsigned int u; } x; x.f = f;
  unsigned int r = x.u + 0x7fffu + ((x.u >> 16) & 1u);
  return (unsigned short)(r >> 16);
}

__device__ __forceinline__ void async_load16(const unsigned short* g, unsigned short* l) {
  __builtin_amdgcn_global_load_lds(
      (const __attribute__((address_space(1))) void*)g,
      (__attribute__((address_space(3))) void*)l, 16, 0, 0);
}

// ---------------- router phase ----------------

// stage 1: partial sums over T in 8 chunks of 128. part[tc][b][c]
__global__ void k_meanpart(const float* __restrict__ x, float* __restrict__ part) {
  int b = blockIdx.x >> 3, tc = blockIdx.x & 7;
  int c4 = threadIdx.x * 4;
  const float* xp = x + (size_t)b * T_ * C_ + (size_t)tc * 128 * C_ + c4;
  v4f s = {0.f, 0.f, 0.f, 0.f};
  for (int t = 0; t < 128; ++t) s += *(const v4f*)(xp + (size_t)t * C_);
  *(v4f*)(part + (size_t)(tc * B_ + b) * C_ + c4) = s;
}

// stage 2: single block: seq_rep, logits, softmax, top-2, weights, loss
__global__ void k_router(const float* __restrict__ part, const float* __restrict__ rw,
                         int* __restrict__ sel, float* __restrict__ wv,
                         float* __restrict__ loss_out) {
  __shared__ float seq[B_ * C_];
  __shared__ float pr[B_][E_];
  __shared__ int ss[B_][2];
  const int tid = threadIdx.x;
  for (int idx = tid; idx < B_ * C_; idx += 256) {
    float s = 0.f;
#pragma unroll
    for (int tc = 0; tc < 8; ++tc) s += part[(size_t)tc * B_ * C_ + idx];
    seq[idx] = s * (1.0f / T_);
  }
  __syncthreads();
  if (tid < B_ * E_) {
    int b = tid >> 3, e = tid & 7;
    float acc = 0.f;
    for (int c = 0; c < C_; ++c) acc += seq[b * C_ + c] * rw[e * C_ + c];
    pr[b][e] = acc;
  }
  __syncthreads();
  if (tid < B_) {
    int b = tid;
    float mx = pr[b][0];
#pragma unroll
    for (int e = 1; e < E_; ++e) mx = fmaxf(mx, pr[b][e]);
    float p[E_]; float sum = 0.f;
#pragma unroll
    for (int e = 0; e < E_; ++e) { p[e] = __expf(pr[b][e] - mx); sum += p[e]; }
    float inv = 1.0f / sum;
#pragma unroll
    for (int e = 0; e < E_; ++e) { p[e] *= inv; pr[b][e] = p[e]; }
    int i0 = 0;
#pragma unroll
    for (int e = 1; e < E_; ++e) if (p[e] > p[i0]) i0 = e;
    int i1 = (i0 == 0) ? 1 : 0;
#pragma unroll
    for (int e = 0; e < E_; ++e) if (e != i0 && p[e] > p[i1]) i1 = e;
    float s2 = p[i0] + p[i1];
    sel[b * 2 + 0] = i0; sel[b * 2 + 1] = i1;
    wv[b * 2 + 0] = p[i0] / s2; wv[b * 2 + 1] = p[i1] / s2;
    ss[b][0] = i0; ss[b][1] = i1;
  }
  __syncthreads();
  if (tid == 0) {
    float loss = 0.f;
    for (int e = 0; e < E_; ++e) {
      float imp = 0.f, ld = 0.f;
      for (int b = 0; b < B_; ++b) {
        imp += pr[b][e];
        ld += ((ss[b][0] == e) || (ss[b][1] == e)) ? 1.f : 0.f;
      }
      loss += (imp / (float)B_) * (ld / (float)B_);
    }
    loss_out[0] = loss * (float)E_;
  }
}

// ---------------- conversion / transpose ----------------

__global__ void k_castx(const float* __restrict__ x, unsigned short* __restrict__ xb) {
  size_t i = (size_t)blockIdx.x * 256 + threadIdx.x;
  v4f v = *(const v4f*)(x + i * 4);
  ushort4 o;
  o.x = f2bf(v.x); o.y = f2bf(v.y); o.z = f2bf(v.z); o.w = f2bf(v.w);
  *(ushort4*)(xb + i * 4) = o;
}

// per-slice [R][Cc] f32 -> [Cc][R] bf16
__global__ void k_transpose(const float* __restrict__ src, unsigned short* __restrict__ dst,
                            int R, int Cc) {
  __shared__ float tile[32][33];
  const size_t sl = (size_t)blockIdx.z * R * Cc;
  int c0 = blockIdx.x * 32, r0 = blockIdx.y * 32;
  int tx = threadIdx.x & 31, ty = threadIdx.x >> 5;
#pragma unroll
  for (int j = ty; j < 32; j += 8)
    tile[j][tx] = src[sl + (size_t)(r0 + j) * Cc + c0 + tx];
  __syncthreads();
#pragma unroll
  for (int j = ty; j < 32; j += 8)
    dst[sl + (size_t)(c0 + j) * R + r0 + tx] = f2bf(tile[tx][j]);
}

// ---------------- GEMM core (m97 recipe: 128x128 tile, BK=32, bf16 MFMA) ----------------
// A: [M][Kd] bf16 row-major (lda=Kd). Bt: [N][Kd] bf16 row-major (ldb=Kd). Both staged
// via global_load_lds width=16 into LDS [128][32]; frags read as ds_read_b128.

__device__ __forceinline__ void gemm_seg(const unsigned short* A, int lda,
                                         const unsigned short* Bt, int ldb,
                                         int Kd, int row0, int col0,
                                         unsigned short* As, unsigned short* Bs,
                                         v4f (&acc)[4][4]) {
  const int tid = threadIdx.x;
  const int lane = tid & 63;
  const int wave = __builtin_amdgcn_readfirstlane(tid >> 6);
  const int r = lane & 15, q = lane >> 4;
  const int wm = wave & 1, wn = wave >> 1;
  const int lrow = lane >> 2, lch = lane & 3;
  const bool doA = (wave < 2);
  const int jb = (wave & 1) * 4;
  const int gld = doA ? lda : ldb;
  const unsigned short* gbase =
      (doA ? (A + (size_t)row0 * lda) : (Bt + (size_t)col0 * ldb)) +
      (size_t)(jb * 16 + lrow) * gld + lch * 8;
  unsigned short* lbase = (doA ? As : Bs) + jb * 512;

  for (int kc = 0; kc < Kd; kc += 32) {
    const unsigned short* g = gbase + kc;
    async_load16(g + 0 * 16 * (size_t)gld, lbase + 0 * 512);
    async_load16(g + 1 * 16 * (size_t)gld, lbase + 1 * 512);
    async_load16(g + 2 * 16 * (size_t)gld, lbase + 2 * 512);
    async_load16(g + 3 * 16 * (size_t)gld, lbase + 3 * 512);
    __syncthreads();
    v8s af[4], bf[4];
#pragma unroll
    for (int i = 0; i < 4; ++i)
      af[i] = *(const v8s*)&As[(wm * 64 + i * 16 + r) * 32 + q * 8];
#pragma unroll
    for (int j = 0; j < 4; ++j)
      bf[j] = *(const v8s*)&Bs[(wn * 64 + j * 16 + r) * 32 + q * 8];
#pragma unroll
    for (int i = 0; i < 4; ++i)
#pragma unroll
      for (int j = 0; j < 4; ++j)
        acc[i][j] = __builtin_amdgcn_mfma_f32_16x16x32_bf16(af[i], bf[j], acc[i][j], 0, 0, 0);
    __syncthreads();
  }
}

// GEMM1: h[bk] = w[bk] * gelu(x[b] @ w_fc[sel[bk]])   -> bf16 [T][H]
__global__ __launch_bounds__(256, 2) void k_gemm1(
    const unsigned short* __restrict__ Xb, const unsigned short* __restrict__ Wfct,
    const int* __restrict__ sel, const float* __restrict__ wv,
    unsigned short* __restrict__ Hout) {
  __shared__ unsigned short As[128 * 32];
  __shared__ unsigned short Bs[128 * 32];
  const int bk = blockIdx.z;
  const int e = sel[bk];
  const float wgt = wv[bk];
  const int row0 = blockIdx.y * 128, col0 = blockIdx.x * 128;
  v4f acc[4][4];
#pragma unroll
  for (int i = 0; i < 4; ++i)
#pragma unroll
    for (int j = 0; j < 4; ++j) acc[i][j] = (v4f){0.f, 0.f, 0.f, 0.f};

  gemm_seg(Xb + (size_t)(bk >> 1) * T_ * C_, C_, Wfct + (size_t)e * H_ * C_, C_,
           C_, row0, col0, As, Bs, acc);

  const int lane = threadIdx.x & 63;
  const int wave = threadIdx.x >> 6;
  const int r = lane & 15, q = lane >> 4;
  const int wm = wave & 1, wn = wave >> 1;
  unsigned short* Co = Hout + (size_t)bk * T_ * H_;
#pragma unroll
  for (int i = 0; i < 4; ++i) {
    int gr = row0 + wm * 64 + i * 16 + q * 4;
#pragma unroll
    for (int j = 0; j < 4; ++j) {
      int gc = col0 + wn * 64 + j * 16 + r;
#pragma unroll
      for (int p = 0; p < 4; ++p) {
        float u = acc[i][j][p];
        float y = 0.7978845608028654f * (u + 0.044715f * u * u * u);
        float t = 1.0f - 2.0f / (__expf(2.0f * y) + 1.0f);
        float gv = 0.5f * u * (1.0f + t) * wgt;
        Co[(size_t)(gr + p) * H_ + gc] = f2bf(gv);
      }
    }
  }
}

// GEMM2: out[b] = sum_k h[b,k] @ w_proj[sel[b,k]]   (weights already folded into h)
__global__ __launch_bounds__(256, 2) void k_gemm2(
    const unsigned short* __restrict__ Hin, const unsigned short* __restrict__ Wpt,
    const int* __restrict__ sel, float* __restrict__ Out) {
  __shared__ unsigned short As[128 * 32];
  __shared__ unsigned short Bs[128 * 32];
  const int b = blockIdx.z;
  const int row0 = blockIdx.y * 128, col0 = blockIdx.x * 128;
  v4f acc[4][4];
#pragma unroll
  for (int i = 0; i < 4; ++i)
#pragma unroll
    for (int j = 0; j < 4; ++j) acc[i][j] = (v4f){0.f, 0.f, 0.f, 0.f};

  for (int k = 0; k < 2; ++k) {
    int e = sel[b * 2 + k];
    gemm_seg(Hin + (size_t)(b * 2 + k) * T_ * H_, H_, Wpt + (size_t)e * C_ * H_, H_,
             H_, row0, col0, As, Bs, acc);
  }

  const int lane = threadIdx.x & 63;
  const int wave = threadIdx.x >> 6;
  const int r = lane & 15, q = lane >> 4;
  const int wm = wave & 1, wn = wave >> 1;
  float* Co = Out + (size_t)b * T_ * C_;
#pragma unroll
  for (int i = 0; i < 4; ++i) {
    int gr = row0 + wm * 64 + i * 16 + q * 4;
#pragma unroll
    for (int j = 0; j < 4; ++j) {
      int gc = col0 + wn * 64 + j * 16 + r;
#pragma unroll
      for (int p = 0; p < 4; ++p)
        Co[(size_t)(gr + p) * C_ + gc] = acc[i][j][p];
    }
  }
}

// ---------------- launch ----------------

extern "C" void kernel_launch(void* const* d_in, const int* in_sizes, int n_in,
                              void* d_out, int out_size, void* d_ws, size_t ws_size,
                              hipStream_t stream) {
  const float* x   = (const float*)d_in[0];
  const float* rw  = (const float*)d_in[1];
  const float* wfc = (const float*)d_in[2];
  const float* wpj = (const float*)d_in[3];
  float* out = (float*)d_out;
  char* ws = (char*)d_ws;

  // workspace layout (bytes)
  float*          part = (float*)(ws + 0);                        // 8*8*1024*4   = 256 KB
  int*            sel  = (int*)(ws + (262144));                   // 64 B
  float*          wv   = (float*)(ws + (262144 + 64));            // 64 B
  unsigned short* xb   = (unsigned short*)(ws + 524288);          // 16 MB  bf16 x
  unsigned short* wfct = (unsigned short*)(ws + 524288 + 16777216);            // 64 MB
  unsigned short* wpjt = (unsigned short*)(ws + 524288 + 16777216 + 67108864); // 64 MB
  unsigned short* h    = (unsigned short*)(ws + 524288 + 16777216 + 2*67108864ll); // 128 MB

  k_meanpart<<<dim3(B_ * 8), dim3(256), 0, stream>>>(x, part);
  k_router<<<dim3(1), dim3(256), 0, stream>>>(part, rw, sel, wv,
                                              out + (size_t)B_ * T_ * C_);
  k_castx<<<dim3((B_ * T_ * C_ / 4) / 256), dim3(256), 0, stream>>>(x, xb);
  // w_fc [E][C][H] -> [E][H][C] bf16
  k_transpose<<<dim3(H_ / 32, C_ / 32, E_), dim3(256), 0, stream>>>(wfc, wfct, C_, H_);
  // w_proj [E][H][C] -> [E][C][H] bf16
  k_transpose<<<dim3(C_ / 32, H_ / 32, E_), dim3(256), 0, stream>>>(wpj, wpjt, H_, C_);

  k_gemm1<<<dim3(H_ / 128, T_ / 128, B_ * 2), dim3(256), 0, stream>>>(xb, wfct, sel, wv, h);
  k_gemm2<<<dim3(C_ / 128, T_ / 128, B_), dim3(256), 0, stream>>>(h, wpjt, sel, out);
}